// Round 4
// baseline (475.792 us; speedup 1.0000x reference)
//
#include <hip/hip_runtime.h>

typedef __attribute__((ext_vector_type(8))) short short8v;
typedef __attribute__((ext_vector_type(4))) float f32x4;
typedef __attribute__((ext_vector_type(4))) unsigned int uint4v;
typedef __attribute__((ext_vector_type(4))) float float4v;

__device__ __forceinline__ unsigned short f2bf(float f) {
  union { float f; unsigned u; } v; v.f = f;
  unsigned r = v.u + 0x7fffu + ((v.u >> 16) & 1u);
  return (unsigned short)(r >> 16);
}
__device__ __forceinline__ float bf2f(unsigned short h) {
  union { unsigned u; float f; } v; v.u = ((unsigned)h) << 16;
  return v.f;
}
__device__ __forceinline__ unsigned pack2(float a, float b) {
  return (unsigned)f2bf(a) | ((unsigned)f2bf(b) << 16);
}

__device__ __forceinline__ void gload_lds16(const void* g, void* l) {
  __builtin_amdgcn_global_load_lds(
      (const __attribute__((address_space(1))) void*)g,
      (__attribute__((address_space(3))) void*)l, 16, 0, 0);
}

#define SBAR() __builtin_amdgcn_s_barrier()
#define LGKM(n) do { asm volatile("s_waitcnt lgkmcnt(" #n ")" ::: "memory"); \
                     __builtin_amdgcn_sched_barrier(0); } while (0)
#define VMW(n) asm volatile("s_waitcnt vmcnt(" #n ")" ::: "memory")

// ---------------- x: f32 -> bf16 streaming convert
__global__ void f32_to_bf16(const float* __restrict__ in, unsigned short* __restrict__ out,
                            size_t n8) {
  size_t i = (size_t)blockIdx.x * blockDim.x + threadIdx.x;
  const size_t stride = (size_t)gridDim.x * blockDim.x;
  for (; i < n8; i += stride) {
    const float4v* p = (const float4v*)(in + i * 8);
    float4v a = p[0], b = p[1];
    uint4v r;
    r.x = pack2(a.x, a.y); r.y = pack2(a.z, a.w);
    r.z = pack2(b.x, b.y); r.w = pack2(b.z, b.w);
    *(uint4v*)(out + i * 8) = r;
  }
}

// ---------------- weight transpose + convert: W(K,N) f32 -> WT(N,K) bf16
__global__ void transpose_bf16(const float* __restrict__ W, unsigned short* __restrict__ WT,
                               int K, int N) {
  __shared__ float t[32][33];
  const int kb = blockIdx.x * 32, nb = blockIdx.y * 32;
  const int tx = threadIdx.x, ty = threadIdx.y;
  #pragma unroll
  for (int y = 0; y < 4; ++y)
    t[ty + y*8][tx] = W[(size_t)(kb + ty + y*8) * N + nb + tx];
  __syncthreads();
  #pragma unroll
  for (int y = 0; y < 4; ++y) {
    const int n = nb + ty + y*8;
    WT[(size_t)n * K + kb + tx] = f2bf(t[tx][ty + y*8]);
  }
}

__global__ void trig_kernel(const float* __restrict__ theta, float* __restrict__ ct,
                            float* __restrict__ st, int n) {
  const int i = blockIdx.x * 256 + threadIdx.x;
  if (i < n) {
    float s, c;
    sincosf(theta[i], &s, &c);
    ct[i] = c; st[i] = s;
  }
}

// ---------------- butterfly over last dim 256 (8 stages)
__global__ void butterfly_kernel(const unsigned short* __restrict__ X,
                                 unsigned short* __restrict__ Y,
                                 const float* __restrict__ ct, const float* __restrict__ st) {
  __shared__ float L[2][256];
  const int tid = threadIdx.x;
  const size_t base = (size_t)blockIdx.x * 512;
  const unsigned v = *(const unsigned*)(X + base + tid * 2);
  const int r = tid >> 7;
  const int col = (tid * 2) & 255;
  L[r][col]     = bf2f((unsigned short)(v & 0xffffu));
  L[r][col + 1] = bf2f((unsigned short)(v >> 16));
  __syncthreads();
  const int p = tid & 127;
  #pragma unroll
  for (int s = 0; s < 8; ++s) {
    const int stride = 1 << s;
    const int t = p & (stride - 1);
    const int i = ((p >> s) << (s + 1)) + t;
    const int j = i + stride;
    const float c  = ct[s * 128 + p];
    const float sn = st[s * 128 + p];
    const float a = L[r][i], b = L[r][j];
    L[r][i] = c * a - sn * b;
    L[r][j] = sn * a + c * b;
    __syncthreads();
  }
  const unsigned lo = f2bf(L[r][col]);
  const unsigned hi = f2bf(L[r][col + 1]);
  *(unsigned*)(Y + base + tid * 2) = lo | (hi << 16);
}

// ---------------- small GEMM (128x128, m97 structure) for L2/L3
template<bool RELU, bool OUT_F32>
__global__ __launch_bounds__(256) void gemm_kernel(
    const unsigned short* __restrict__ A, const unsigned short* __restrict__ BT,
    const float* __restrict__ bias, void* __restrict__ Cp,
    int M, int N, int K)
{
  __shared__ __align__(16) unsigned short As[128 * 32];
  __shared__ __align__(16) unsigned short Bs[128 * 32];
  const int tid = threadIdx.x;
  const int lane = tid & 63;
  const int w = tid >> 6;
  const int wm = w >> 1, wn = w & 1;
  const int n0 = blockIdx.x * 128;
  const int m0 = blockIdx.y * 128;
  const int g4 = lane >> 4;
  const int ml = lane & 15;

  f32x4 acc[4][4];
  #pragma unroll
  for (int i = 0; i < 4; ++i)
    #pragma unroll
    for (int n = 0; n < 4; ++n)
      #pragma unroll
      for (int e = 0; e < 4; ++e)
        acc[i][n][e] = 0.0f;

  const int nkt = K >> 5;
  const int srow = w * 32 + (lane >> 2);
  const int scol = (lane & 3) * 8;

  for (int kt = 0; kt < nkt; ++kt) {
    const int k0 = kt << 5;
    #pragma unroll
    for (int q = 0; q < 2; ++q) {
      const unsigned short* gb = BT + (size_t)(n0 + srow + q * 16) * K + k0 + scol;
      gload_lds16(gb, Bs + w * 1024 + q * 512);
      const unsigned short* ga = A + (size_t)(m0 + srow + q * 16) * K + k0 + scol;
      gload_lds16(ga, As + w * 1024 + q * 512);
    }
    __syncthreads();
    short8v af[4], bf[4];
    #pragma unroll
    for (int i = 0; i < 4; ++i)
      af[i] = *(const short8v*)(As + (wm * 64 + i * 16 + ml) * 32 + g4 * 8);
    #pragma unroll
    for (int n = 0; n < 4; ++n)
      bf[n] = *(const short8v*)(Bs + (wn * 64 + n * 16 + ml) * 32 + g4 * 8);
    #pragma unroll
    for (int i = 0; i < 4; ++i)
      #pragma unroll
      for (int n = 0; n < 4; ++n)
        acc[i][n] = __builtin_amdgcn_mfma_f32_16x16x32_bf16(af[i], bf[n], acc[i][n], 0, 0, 0);
    __syncthreads();
  }
  #pragma unroll
  for (int n = 0; n < 4; ++n) {
    const int col = n0 + wn * 64 + n * 16 + ml;
    const float bv = bias[col];
    #pragma unroll
    for (int i = 0; i < 4; ++i) {
      const int rowb = m0 + wm * 64 + i * 16 + g4 * 4;
      #pragma unroll
      for (int r = 0; r < 4; ++r) {
        float v = acc[i][n][r] + bv;
        if constexpr (RELU) v = fmaxf(v, 0.0f);
        if constexpr (OUT_F32)
          ((float*)Cp)[(size_t)(rowb + r) * N + col] = v;
        else
          ((unsigned short*)Cp)[(size_t)(rowb + r) * N + col] = f2bf(v);
      }
    }
  }
}

// ---------------- big GEMM: 256x256 8-phase, read-ahead-by-1 + counted waits
template<int MI0, int NI0>
__device__ __forceinline__ void mfma_quad(f32x4 (&acc)[8][4], const short8v (&a)[4][2],
                                          const short8v (&b)[2][2]) {
  __builtin_amdgcn_s_setprio(1);
  #pragma unroll
  for (int mi = 0; mi < 4; ++mi)
    #pragma unroll
    for (int ni = 0; ni < 2; ++ni) {
      acc[MI0+mi][NI0+ni] = __builtin_amdgcn_mfma_f32_16x16x32_bf16(
          a[mi][0], b[ni][0], acc[MI0+mi][NI0+ni], 0, 0, 0);
      acc[MI0+mi][NI0+ni] = __builtin_amdgcn_mfma_f32_16x16x32_bf16(
          a[mi][1], b[ni][1], acc[MI0+mi][NI0+ni], 0, 0, 0);
    }
  __builtin_amdgcn_s_setprio(0);
}

template<bool RELU, bool OUT_F32>
__global__ __launch_bounds__(512, 2) void gemm256(
    const unsigned short* __restrict__ A, const unsigned short* __restrict__ BT,
    const float* __restrict__ bias, void* __restrict__ Cp,
    int M, int N, int K)
{
  __shared__ __align__(16) unsigned char lds[131072];
  const int tid = threadIdx.x;
  const int lane = tid & 63, w = tid >> 6;
  const int wm = w >> 2, wn = w & 3;
  const int ml = lane & 15, g4 = lane >> 4;

  // bijective XCD-chunked swizzle (nwg % 8 == 0 for our grids)
  const int nx = gridDim.x;
  const int nwg = nx * (int)gridDim.y;
  const int bid = blockIdx.y * nx + blockIdx.x;
  const int cpx = nwg >> 3;
  const int swz = (bid & 7) * cpx + (bid >> 3);
  const int n0 = (swz % nx) * 256;
  const int m0 = (swz / nx) * 256;

  // staging: linear LDS dest; source col pre-swizzled (involution)
  const int rloc = w * 8 + (lane >> 3);
  const int scol = ((lane & 7) ^ (lane >> 3)) * 8;
  const int ldst = w * 1024;

  // fragment reads: byte = row*128 + ((kk*64+g4*16) ^ ((row&7)<<4))
  const int off0 = (g4 * 16) ^ ((ml & 7) << 4);
  const int aoff = (wm * 128 + ml) * 128 + off0;
  const int boff = (wn * 64 + ml) * 128 + off0;

  const int NT = K >> 6;
  const int NJ = NT >> 1;

  f32x4 acc[8][4];
  #pragma unroll
  for (int mi = 0; mi < 8; ++mi)
    #pragma unroll
    for (int ni = 0; ni < 4; ++ni)
      #pragma unroll
      for (int e = 0; e < 4; ++e)
        acc[mi][ni][e] = 0.0f;

  auto stA = [&](int d, int h, int t) {
    const unsigned short* g0 = A + (size_t)(m0 + h * 128 + rloc) * K + t * 64 + scol;
    unsigned char* l0 = lds + d * 65536 + h * 16384 + ldst;
    gload_lds16(g0, l0);
    gload_lds16(g0 + (size_t)64 * K, l0 + 8192);
  };
  auto stB = [&](int d, int h, int t) {
    const unsigned short* g0 = BT + (size_t)(n0 + h * 128 + rloc) * K + t * 64 + scol;
    unsigned char* l0 = lds + d * 65536 + 32768 + h * 16384 + ldst;
    gload_lds16(g0, l0);
    gload_lds16(g0 + (size_t)64 * K, l0 + 8192);
  };
  auto rdA = [&](short8v (&dst)[4][2], int d, int mh) {
    #pragma unroll
    for (int mi = 0; mi < 4; ++mi) {
      const int ab = d * 65536 + aoff + (mh * 4 + mi) * 2048;
      dst[mi][0] = *(const short8v*)(lds + ab);
      dst[mi][1] = *(const short8v*)(lds + (ab ^ 64));
    }
  };
  auto rdB = [&](short8v (&dst)[2][2], int d, int nh) {
    #pragma unroll
    for (int ni = 0; ni < 2; ++ni) {
      const int bb = d * 65536 + 32768 + boff + (nh * 2 + ni) * 2048;
      dst[ni][0] = *(const short8v*)(lds + bb);
      dst[ni][1] = *(const short8v*)(lds + (bb ^ 64));
    }
  };

  short8v A0[4][2], A1[4][2], B0[2][2], B1[2][2];

  // prologue: full t0 -> buf0; B halves of t1 -> buf1; drain t0; preload q00 frags.
  stB(0, 0, 0); stB(0, 1, 0); stA(0, 0, 0); stA(0, 1, 0);
  stB(1, 0, 1); stB(1, 1, 1);
  VMW(4);
  SBAR();
  rdA(A0, 0, 0); rdB(B0, 0, 0);   // 12 reads for p1's MFMA

  for (int j = 0; j < NJ; ++j) {
    const int t1 = 2 * j + 1;
    const int t2 = (2 * j + 2 < NT) ? 2 * j + 2 : NT - 1;
    const int t3 = (2 * j + 3 < NT) ? 2 * j + 3 : NT - 1;

    // p1: read B1(buf0) | stage A0(t1)->buf1 | MFMA q00(A0,B0)
    rdB(B1, 0, 1);
    stA(1, 0, t1);
    SBAR(); LGKM(4);
    mfma_quad<0, 0>(acc, A0, B0);
    SBAR();
    // p2: read A1(buf0) | stage A1(t1)->buf1 | MFMA q01(A0,B1)
    rdA(A1, 0, 1);
    stA(1, 1, t1);
    SBAR(); LGKM(8);
    mfma_quad<0, 2>(acc, A0, B1);
    SBAR();
    // p3: stage B0(t2)->buf0 | MFMA q10(A1,B0) | drain buf1/t1 (vmcnt 2)
    stB(0, 0, t2);
    SBAR(); LGKM(0);
    mfma_quad<4, 0>(acc, A1, B0);
    VMW(2);
    SBAR();
    // p4: read A0,B0 (buf1/t1) | stage B1(t2)->buf0 | MFMA q11(A1,B1)
    rdA(A0, 1, 0); rdB(B0, 1, 0);
    stB(0, 1, t2);
    SBAR(); LGKM(12);
    mfma_quad<4, 2>(acc, A1, B1);
    SBAR();
    // p5: read B1(buf1) | stage A0(t2)->buf0 | MFMA q00(A0,B0)
    rdB(B1, 1, 1);
    stA(0, 0, t2);
    SBAR(); LGKM(4);
    mfma_quad<0, 0>(acc, A0, B0);
    SBAR();
    // p6: read A1(buf1) | stage A1(t2)->buf0 | MFMA q01(A0,B1)
    rdA(A1, 1, 1);
    stA(0, 1, t2);
    SBAR(); LGKM(8);
    mfma_quad<0, 2>(acc, A0, B1);
    SBAR();
    // p7: stage B0(t3)->buf1 | MFMA q10(A1,B0) | drain buf0/t2 (vmcnt 2)
    stB(1, 0, t3);
    SBAR(); LGKM(0);
    mfma_quad<4, 0>(acc, A1, B0);
    VMW(2);
    SBAR();
    // p8: read A0,B0 (buf0/t2) | stage B1(t3)->buf1 | MFMA q11(A1,B1)
    rdA(A0, 0, 0); rdB(B0, 0, 0);
    stB(1, 1, t3);
    SBAR(); LGKM(12);
    mfma_quad<4, 2>(acc, A1, B1);
    SBAR();
  }

  // epilogue: C/D layout col=lane&15, row=(lane>>4)*4+reg
  #pragma unroll
  for (int ni = 0; ni < 4; ++ni) {
    const int col = n0 + wn * 64 + ni * 16 + ml;
    const float bv = bias[col];
    #pragma unroll
    for (int mi = 0; mi < 8; ++mi) {
      const int rowb = m0 + wm * 128 + mi * 16 + g4 * 4;
      #pragma unroll
      for (int r = 0; r < 4; ++r) {
        float v = acc[mi][ni][r] + bv;
        if constexpr (RELU) v = fmaxf(v, 0.0f);
        if constexpr (OUT_F32)
          ((float*)Cp)[(size_t)(rowb + r) * N + col] = v;
        else
          ((unsigned short*)Cp)[(size_t)(rowb + r) * N + col] = f2bf(v);
      }
    }
  }
}

extern "C" void kernel_launch(void* const* d_in, const int* in_sizes, int n_in,
                              void* d_out, int out_size, void* d_ws, size_t ws_size,
                              hipStream_t stream) {
  const float* x      = (const float*)d_in[0];
  const float* enc_w0 = (const float*)d_in[1];
  const float* enc_b0 = (const float*)d_in[2];
  const float* enc_w1 = (const float*)d_in[3];
  const float* enc_b1 = (const float*)d_in[4];
  const float* theta  = (const float*)d_in[5];
  const float* dec_w0 = (const float*)d_in[6];
  const float* dec_b0 = (const float*)d_in[7];
  const float* out_w  = (const float*)d_in[8];
  const float* out_b  = (const float*)d_in[9];
  float* out = (float*)d_out;

  char* ws = (char*)d_ws;
  unsigned short* xb  = (unsigned short*)(ws);               // 16384x4096 bf16
  unsigned short* wt0 = (unsigned short*)(ws + 134217728);   // 1024x4096
  unsigned short* wt1 = (unsigned short*)(ws + 142606336);   // 256x1024
  unsigned short* wt2 = (unsigned short*)(ws + 143130624);   // 1024x256
  unsigned short* wt3 = (unsigned short*)(ws + 143654912);   // 4096x1024
  unsigned short* h1  = (unsigned short*)(ws + 152043520);   // 16384x1024 (reused as h3)
  unsigned short* h2  = (unsigned short*)(ws + 185597952);   // 16384x256
  unsigned short* h2b = (unsigned short*)(ws + 193986560);   // 16384x256
  unsigned short* h3  = h1;
  float* ct = (float*)(ws + 202375168);
  float* st = ct + 1024;

  const int B = 16384;

  f32_to_bf16<<<2048, 256, 0, stream>>>(x, xb, (size_t)B * 4096 / 8);
  transpose_bf16<<<dim3(4096/32, 1024/32), dim3(32, 8), 0, stream>>>(enc_w0, wt0, 4096, 1024);
  transpose_bf16<<<dim3(1024/32,  256/32), dim3(32, 8), 0, stream>>>(enc_w1, wt1, 1024, 256);
  transpose_bf16<<<dim3( 256/32, 1024/32), dim3(32, 8), 0, stream>>>(dec_w0, wt2, 256, 1024);
  transpose_bf16<<<dim3(1024/32, 4096/32), dim3(32, 8), 0, stream>>>(out_w,  wt3, 1024, 4096);
  trig_kernel<<<4, 256, 0, stream>>>(theta, ct, st, 1024);

  // L1: h1 = relu(xb @ enc_w0 + b0)  [256-tile 8-phase]
  gemm256<true,  false><<<dim3(1024/256, B/256), 512, 0, stream>>>(xb, wt0, enc_b0, h1, B, 1024, 4096);
  // L2: h2 = relu(h1 @ enc_w1 + b1)  [128-tile]
  gemm_kernel<true,  false><<<dim3( 256/128, B/128), 256, 0, stream>>>(h1, wt1, enc_b1, h2, B, 256, 1024);
  // butterfly
  butterfly_kernel<<<B/2, 256, 0, stream>>>(h2, h2b, ct, st);
  // L3: h3 = relu(h2b @ dec_w0 + db0)  [128-tile]
  gemm_kernel<true,  false><<<dim3(1024/128, B/128), 256, 0, stream>>>(h2b, wt2, dec_b0, h3, B, 1024, 256);
  // L4: out = h3 @ out_w + out_b  [256-tile 8-phase, f32 out]
  gemm256<false, true ><<<dim3(4096/256, B/256), 512, 0, stream>>>(h3, wt3, out_b, out, B, 4096, 1024);
}

// Round 5
// 393.764 us; speedup vs baseline: 1.2083x; 1.2083x over previous
//
#include <hip/hip_runtime.h>

typedef __attribute__((ext_vector_type(8))) short short8v;
typedef __attribute__((ext_vector_type(4))) float f32x4;
typedef __attribute__((ext_vector_type(4))) unsigned int uint4v;
typedef __attribute__((ext_vector_type(4))) float float4v;

__device__ __forceinline__ unsigned short f2bf(float f) {
  union { float f; unsigned u; } v; v.f = f;
  unsigned r = v.u + 0x7fffu + ((v.u >> 16) & 1u);
  return (unsigned short)(r >> 16);
}
__device__ __forceinline__ float bf2f(unsigned short h) {
  union { unsigned u; float f; } v; v.u = ((unsigned)h) << 16;
  return v.f;
}
__device__ __forceinline__ unsigned pack2(float a, float b) {
  return (unsigned)f2bf(a) | ((unsigned)f2bf(b) << 16);
}

__device__ __forceinline__ void gload_lds16(const void* g, void* l) {
  __builtin_amdgcn_global_load_lds(
      (const __attribute__((address_space(1))) void*)g,
      (__attribute__((address_space(3))) void*)l, 16, 0, 0);
}

#define SBAR() __builtin_amdgcn_s_barrier()
#define SCHED0() __builtin_amdgcn_sched_barrier(0)
#define LGKM(n) do { asm volatile("s_waitcnt lgkmcnt(" #n ")" ::: "memory"); \
                     __builtin_amdgcn_sched_barrier(0); } while (0)
#define VMW(n) asm volatile("s_waitcnt vmcnt(" #n ")" ::: "memory")

// ---------------- x: f32 -> bf16 streaming convert (nt loads keep L3 for xb)
__global__ void f32_to_bf16(const float* __restrict__ in, unsigned short* __restrict__ out,
                            size_t n8) {
  size_t i = (size_t)blockIdx.x * blockDim.x + threadIdx.x;
  const size_t stride = (size_t)gridDim.x * blockDim.x;
  for (; i < n8; i += stride) {
    const float4v* p = (const float4v*)(in + i * 8);
    float4v a = __builtin_nontemporal_load(p);
    float4v b = __builtin_nontemporal_load(p + 1);
    uint4v r;
    r.x = pack2(a.x, a.y); r.y = pack2(a.z, a.w);
    r.z = pack2(b.x, b.y); r.w = pack2(b.z, b.w);
    *(uint4v*)(out + i * 8) = r;
  }
}

// ---------------- weight transpose + convert: W(K,N) f32 -> WT(N,K) bf16
__global__ void transpose_bf16(const float* __restrict__ W, unsigned short* __restrict__ WT,
                               int K, int N) {
  __shared__ float t[32][33];
  const int kb = blockIdx.x * 32, nb = blockIdx.y * 32;
  const int tx = threadIdx.x, ty = threadIdx.y;
  #pragma unroll
  for (int y = 0; y < 4; ++y)
    t[ty + y*8][tx] = W[(size_t)(kb + ty + y*8) * N + nb + tx];
  __syncthreads();
  #pragma unroll
  for (int y = 0; y < 4; ++y) {
    const int n = nb + ty + y*8;
    WT[(size_t)n * K + kb + tx] = f2bf(t[tx][ty + y*8]);
  }
}

__global__ void trig_kernel(const float* __restrict__ theta, float* __restrict__ ct,
                            float* __restrict__ st, int n) {
  const int i = blockIdx.x * 256 + threadIdx.x;
  if (i < n) {
    float s, c;
    sincosf(theta[i], &s, &c);
    ct[i] = c; st[i] = s;
  }
}

// ---------------- butterfly over last dim 256 (8 stages)
__global__ void butterfly_kernel(const unsigned short* __restrict__ X,
                                 unsigned short* __restrict__ Y,
                                 const float* __restrict__ ct, const float* __restrict__ st) {
  __shared__ float L[2][256];
  const int tid = threadIdx.x;
  const size_t base = (size_t)blockIdx.x * 512;
  const unsigned v = *(const unsigned*)(X + base + tid * 2);
  const int r = tid >> 7;
  const int col = (tid * 2) & 255;
  L[r][col]     = bf2f((unsigned short)(v & 0xffffu));
  L[r][col + 1] = bf2f((unsigned short)(v >> 16));
  __syncthreads();
  const int p = tid & 127;
  #pragma unroll
  for (int s = 0; s < 8; ++s) {
    const int stride = 1 << s;
    const int t = p & (stride - 1);
    const int i = ((p >> s) << (s + 1)) + t;
    const int j = i + stride;
    const float c  = ct[s * 128 + p];
    const float sn = st[s * 128 + p];
    const float a = L[r][i], b = L[r][j];
    L[r][i] = c * a - sn * b;
    L[r][j] = sn * a + c * b;
    __syncthreads();
  }
  const unsigned lo = f2bf(L[r][col]);
  const unsigned hi = f2bf(L[r][col + 1]);
  *(unsigned*)(Y + base + tid * 2) = lo | (hi << 16);
}

// ---------------- small GEMM (128x128, m97 structure) for L2/L3
template<bool RELU, bool OUT_F32>
__global__ __launch_bounds__(256) void gemm_kernel(
    const unsigned short* __restrict__ A, const unsigned short* __restrict__ BT,
    const float* __restrict__ bias, void* __restrict__ Cp,
    int M, int N, int K)
{
  __shared__ __align__(16) unsigned short As[128 * 32];
  __shared__ __align__(16) unsigned short Bs[128 * 32];
  const int tid = threadIdx.x;
  const int lane = tid & 63;
  const int w = tid >> 6;
  const int wm = w >> 1, wn = w & 1;
  const int n0 = blockIdx.x * 128;
  const int m0 = blockIdx.y * 128;
  const int g4 = lane >> 4;
  const int ml = lane & 15;

  f32x4 acc[4][4];
  #pragma unroll
  for (int i = 0; i < 4; ++i)
    #pragma unroll
    for (int n = 0; n < 4; ++n)
      #pragma unroll
      for (int e = 0; e < 4; ++e)
        acc[i][n][e] = 0.0f;

  const int nkt = K >> 5;
  const int srow = w * 32 + (lane >> 2);
  const int scol = (lane & 3) * 8;

  for (int kt = 0; kt < nkt; ++kt) {
    const int k0 = kt << 5;
    #pragma unroll
    for (int q = 0; q < 2; ++q) {
      const unsigned short* gb = BT + (size_t)(n0 + srow + q * 16) * K + k0 + scol;
      gload_lds16(gb, Bs + w * 1024 + q * 512);
      const unsigned short* ga = A + (size_t)(m0 + srow + q * 16) * K + k0 + scol;
      gload_lds16(ga, As + w * 1024 + q * 512);
    }
    __syncthreads();
    short8v af[4], bf[4];
    #pragma unroll
    for (int i = 0; i < 4; ++i)
      af[i] = *(const short8v*)(As + (wm * 64 + i * 16 + ml) * 32 + g4 * 8);
    #pragma unroll
    for (int n = 0; n < 4; ++n)
      bf[n] = *(const short8v*)(Bs + (wn * 64 + n * 16 + ml) * 32 + g4 * 8);
    #pragma unroll
    for (int i = 0; i < 4; ++i)
      #pragma unroll
      for (int n = 0; n < 4; ++n)
        acc[i][n] = __builtin_amdgcn_mfma_f32_16x16x32_bf16(af[i], bf[n], acc[i][n], 0, 0, 0);
    __syncthreads();
  }
  #pragma unroll
  for (int n = 0; n < 4; ++n) {
    const int col = n0 + wn * 64 + n * 16 + ml;
    const float bv = bias[col];
    #pragma unroll
    for (int i = 0; i < 4; ++i) {
      const int rowb = m0 + wm * 64 + i * 16 + g4 * 4;
      #pragma unroll
      for (int r = 0; r < 4; ++r) {
        float v = acc[i][n][r] + bv;
        if constexpr (RELU) v = fmaxf(v, 0.0f);
        if constexpr (OUT_F32)
          __builtin_nontemporal_store(v, &((float*)Cp)[(size_t)(rowb + r) * N + col]);
        else
          ((unsigned short*)Cp)[(size_t)(rowb + r) * N + col] = f2bf(v);
      }
    }
  }
}

// ---------------- big GEMM: 256x256 8-phase (R3 dataflow) + in-phase split waits
template<int MI0, int NI0>
__device__ __forceinline__ void mfma8(f32x4 (&acc)[8][4], const short8v (&a)[4],
                                      const short8v (&b)[2]) {
  __builtin_amdgcn_s_setprio(1);
  #pragma unroll
  for (int mi = 0; mi < 4; ++mi)
    #pragma unroll
    for (int ni = 0; ni < 2; ++ni)
      acc[MI0+mi][NI0+ni] = __builtin_amdgcn_mfma_f32_16x16x32_bf16(
          a[mi], b[ni], acc[MI0+mi][NI0+ni], 0, 0, 0);
  __builtin_amdgcn_s_setprio(0);
}

template<bool RELU, bool OUT_F32>
__global__ __launch_bounds__(512, 2) void gemm256(
    const unsigned short* __restrict__ A, const unsigned short* __restrict__ BT,
    const float* __restrict__ bias, void* __restrict__ Cp,
    int M, int N, int K)
{
  __shared__ __align__(16) unsigned char lds[131072];
  const int tid = threadIdx.x;
  const int lane = tid & 63, w = tid >> 6;
  const int wm = w >> 2, wn = w & 3;
  const int ml = lane & 15, g4 = lane >> 4;

  // bijective XCD-chunked swizzle (nwg % 8 == 0 for our grids)
  const int nx = gridDim.x;
  const int nwg = nx * (int)gridDim.y;
  const int bid = blockIdx.y * nx + blockIdx.x;
  const int cpx = nwg >> 3;
  const int swz = (bid & 7) * cpx + (bid >> 3);
  const int n0 = (swz % nx) * 256;
  const int m0 = (swz / nx) * 256;

  // staging: linear LDS dest; source col pre-swizzled (involution)
  const int rloc = w * 8 + (lane >> 3);
  const int scol = ((lane & 7) ^ (lane >> 3)) * 8;
  const int ldst = w * 1024;

  // fragment reads: byte = row*128 + ((kk*64+g4*16) ^ ((row&7)<<4))
  const int off0 = (g4 * 16) ^ ((ml & 7) << 4);
  const int aoff = (wm * 128 + ml) * 128 + off0;
  const int boff = (wn * 64 + ml) * 128 + off0;

  const int NT = K >> 6;
  const int NJ = NT >> 1;

  f32x4 acc[8][4];
  #pragma unroll
  for (int mi = 0; mi < 8; ++mi)
    #pragma unroll
    for (int ni = 0; ni < 4; ++ni)
      #pragma unroll
      for (int e = 0; e < 4; ++e)
        acc[mi][ni][e] = 0.0f;

  auto stA = [&](int d, int h, int t) {
    const unsigned short* g0 = A + (size_t)(m0 + h * 128 + rloc) * K + t * 64 + scol;
    unsigned char* l0 = lds + d * 65536 + h * 16384 + ldst;
    gload_lds16(g0, l0);
    gload_lds16(g0 + (size_t)64 * K, l0 + 8192);
  };
  auto stB = [&](int d, int h, int t) {
    const unsigned short* g0 = BT + (size_t)(n0 + h * 128 + rloc) * K + t * 64 + scol;
    unsigned char* l0 = lds + d * 65536 + 32768 + h * 16384 + ldst;
    gload_lds16(g0, l0);
    gload_lds16(g0 + (size_t)64 * K, l0 + 8192);
  };
  // per-kk fragment reads (named arrays, compile-time indices only)
  auto rdA0 = [&](short8v (&dst)[4], int d, int mh) {
    #pragma unroll
    for (int mi = 0; mi < 4; ++mi)
      dst[mi] = *(const short8v*)(lds + d * 65536 + aoff + (mh * 4 + mi) * 2048);
  };
  auto rdA1 = [&](short8v (&dst)[4], int d, int mh) {
    #pragma unroll
    for (int mi = 0; mi < 4; ++mi)
      dst[mi] = *(const short8v*)(lds + ((d * 65536 + aoff + (mh * 4 + mi) * 2048) ^ 64));
  };
  auto rdB0 = [&](short8v (&dst)[2], int d, int nh) {
    #pragma unroll
    for (int ni = 0; ni < 2; ++ni)
      dst[ni] = *(const short8v*)(lds + d * 65536 + 32768 + boff + (nh * 2 + ni) * 2048);
  };
  auto rdB1 = [&](short8v (&dst)[2], int d, int nh) {
    #pragma unroll
    for (int ni = 0; ni < 2; ++ni)
      dst[ni] = *(const short8v*)(lds + ((d * 65536 + 32768 + boff + (nh * 2 + ni) * 2048) ^ 64));
  };

  short8v aR_0[4], aR_1[4], aS_0[4], aS_1[4];
  short8v bR0_0[2], bR0_1[2], bR1_0[2], bR1_1[2];

  // prologue: full t0 -> buf0; B halves of t1 -> buf1; drain t0.
  stB(0, 0, 0); stB(0, 1, 0); stA(0, 0, 0); stA(0, 1, 0);
  stB(1, 0, 1); stB(1, 1, 1);
  VMW(4);
  SBAR();

  for (int j = 0; j < NJ; ++j) {
    const int t1 = 2 * j + 1;
    const int t2 = (2 * j + 2 < NT) ? 2 * j + 2 : NT - 1;
    const int t3 = (2 * j + 3 < NT) ? 2 * j + 3 : NT - 1;

    // ---- half-iter A: compute buf0 (tile 2j) ----
    // p1: q00; reads A0,B0 (buf0); stage A0(t1)->buf1
    rdB0(bR0_0, 0, 0); rdA0(aR_0, 0, 0);
    SCHED0();
    rdB1(bR0_1, 0, 0); rdA1(aR_1, 0, 0);
    stA(1, 0, t1);
    SBAR(); LGKM(6);
    mfma8<0, 0>(acc, aR_0, bR0_0);
    LGKM(0);
    mfma8<0, 0>(acc, aR_1, bR0_1);
    SBAR();
    // p2: q01; reads B1 (buf0); stage A1(t1)->buf1
    rdB0(bR1_0, 0, 1);
    SCHED0();
    rdB1(bR1_1, 0, 1);
    stA(1, 1, t1);
    SBAR(); LGKM(2);
    mfma8<0, 2>(acc, aR_0, bR1_0);
    LGKM(0);
    mfma8<0, 2>(acc, aR_1, bR1_1);
    SBAR();
    // p3: q10; reads A1 (buf0); stage B0(t2)->buf0 (B of buf0 fully consumed p1/p2)
    rdA0(aS_0, 0, 1);
    SCHED0();
    rdA1(aS_1, 0, 1);
    stB(0, 0, t2);
    SBAR(); LGKM(4);
    mfma8<4, 0>(acc, aS_0, bR0_0);
    LGKM(0);
    mfma8<4, 0>(acc, aS_1, bR0_1);
    SBAR();
    // p4: q11; no reads; stage B1(t2)->buf0; drain t1 halves (vmcnt 4)
    stB(0, 1, t2);
    SBAR();
    mfma8<4, 2>(acc, aS_0, bR1_0);
    mfma8<4, 2>(acc, aS_1, bR1_1);
    VMW(4);
    SBAR();

    // ---- half-iter B: compute buf1 (tile 2j+1) ----
    // p5: q00; reads A0,B0 (buf1); stage A0(t2)->buf0
    rdB0(bR0_0, 1, 0); rdA0(aR_0, 1, 0);
    SCHED0();
    rdB1(bR0_1, 1, 0); rdA1(aR_1, 1, 0);
    stA(0, 0, t2);
    SBAR(); LGKM(6);
    mfma8<0, 0>(acc, aR_0, bR0_0);
    LGKM(0);
    mfma8<0, 0>(acc, aR_1, bR0_1);
    SBAR();
    // p6: q01; reads B1 (buf1); stage A1(t2)->buf0
    rdB0(bR1_0, 1, 1);
    SCHED0();
    rdB1(bR1_1, 1, 1);
    stA(0, 1, t2);
    SBAR(); LGKM(2);
    mfma8<0, 2>(acc, aR_0, bR1_0);
    LGKM(0);
    mfma8<0, 2>(acc, aR_1, bR1_1);
    SBAR();
    // p7: q10; reads A1 (buf1); stage B0(t3)->buf1
    rdA0(aS_0, 1, 1);
    SCHED0();
    rdA1(aS_1, 1, 1);
    stB(1, 0, t3);
    SBAR(); LGKM(4);
    mfma8<4, 0>(acc, aS_0, bR0_0);
    LGKM(0);
    mfma8<4, 0>(acc, aS_1, bR0_1);
    SBAR();
    // p8: q11; no reads; stage B1(t3)->buf1; drain t2 halves (vmcnt 4)
    stB(1, 1, t3);
    SBAR();
    mfma8<4, 2>(acc, aS_0, bR1_0);
    mfma8<4, 2>(acc, aS_1, bR1_1);
    VMW(4);
    SBAR();
  }

  // epilogue: C/D layout col=lane&15, row=(lane>>4)*4+reg
  #pragma unroll
  for (int ni = 0; ni < 4; ++ni) {
    const int col = n0 + wn * 64 + ni * 16 + ml;
    const float bv = bias[col];
    #pragma unroll
    for (int mi = 0; mi < 8; ++mi) {
      const int rowb = m0 + wm * 128 + mi * 16 + g4 * 4;
      #pragma unroll
      for (int r = 0; r < 4; ++r) {
        float v = acc[mi][ni][r] + bv;
        if constexpr (RELU) v = fmaxf(v, 0.0f);
        if constexpr (OUT_F32)
          __builtin_nontemporal_store(v, &((float*)Cp)[(size_t)(rowb + r) * N + col]);
        else
          ((unsigned short*)Cp)[(size_t)(rowb + r) * N + col] = f2bf(v);
      }
    }
  }
}

extern "C" void kernel_launch(void* const* d_in, const int* in_sizes, int n_in,
                              void* d_out, int out_size, void* d_ws, size_t ws_size,
                              hipStream_t stream) {
  const float* x      = (const float*)d_in[0];
  const float* enc_w0 = (const float*)d_in[1];
  const float* enc_b0 = (const float*)d_in[2];
  const float* enc_w1 = (const float*)d_in[3];
  const float* enc_b1 = (const float*)d_in[4];
  const float* theta  = (const float*)d_in[5];
  const float* dec_w0 = (const float*)d_in[6];
  const float* dec_b0 = (const float*)d_in[7];
  const float* out_w  = (const float*)d_in[8];
  const float* out_b  = (const float*)d_in[9];
  float* out = (float*)d_out;

  char* ws = (char*)d_ws;
  unsigned short* xb  = (unsigned short*)(ws);               // 16384x4096 bf16
  unsigned short* wt0 = (unsigned short*)(ws + 134217728);   // 1024x4096
  unsigned short* wt1 = (unsigned short*)(ws + 142606336);   // 256x1024
  unsigned short* wt2 = (unsigned short*)(ws + 143130624);   // 1024x256
  unsigned short* wt3 = (unsigned short*)(ws + 143654912);   // 4096x1024
  unsigned short* h1  = (unsigned short*)(ws + 152043520);   // 16384x1024 (reused as h3)
  unsigned short* h2  = (unsigned short*)(ws + 185597952);   // 16384x256
  unsigned short* h2b = (unsigned short*)(ws + 193986560);   // 16384x256
  unsigned short* h3  = h1;
  float* ct = (float*)(ws + 202375168);
  float* st = ct + 1024;

  const int B = 16384;

  f32_to_bf16<<<2048, 256, 0, stream>>>(x, xb, (size_t)B * 4096 / 8);
  transpose_bf16<<<dim3(4096/32, 1024/32), dim3(32, 8), 0, stream>>>(enc_w0, wt0, 4096, 1024);
  transpose_bf16<<<dim3(1024/32,  256/32), dim3(32, 8), 0, stream>>>(enc_w1, wt1, 1024, 256);
  transpose_bf16<<<dim3( 256/32, 1024/32), dim3(32, 8), 0, stream>>>(dec_w0, wt2, 256, 1024);
  transpose_bf16<<<dim3(1024/32, 4096/32), dim3(32, 8), 0, stream>>>(out_w,  wt3, 1024, 4096);
  trig_kernel<<<4, 256, 0, stream>>>(theta, ct, st, 1024);

  // L1: h1 = relu(xb @ enc_w0 + b0)  [256-tile 8-phase]
  gemm256<true,  false><<<dim3(1024/256, B/256), 512, 0, stream>>>(xb, wt0, enc_b0, h1, B, 1024, 4096);
  // L2: h2 = relu(h1 @ enc_w1 + b1)  [128-tile]
  gemm_kernel<true,  false><<<dim3( 256/128, B/128), 256, 0, stream>>>(h1, wt1, enc_b1, h2, B, 256, 1024);
  // butterfly
  butterfly_kernel<<<B/2, 256, 0, stream>>>(h2, h2b, ct, st);
  // L3: h3 = relu(h2b @ dec_w0 + db0)  [128-tile]
  gemm_kernel<true,  false><<<dim3(1024/128, B/128), 256, 0, stream>>>(h2b, wt2, dec_b0, h3, B, 1024, 256);
  // L4: out = h3 @ out_w + out_b  [256-tile 8-phase, f32 out]
  gemm256<false, true ><<<dim3(4096/256, B/256), 512, 0, stream>>>(h3, wt3, out_b, out, B, 4096, 1024);
}